// Round 3
// baseline (338.795 us; speedup 1.0000x reference)
//
#include <hip/hip_runtime.h>
#include <stdint.h>

// x: (32, 256, 58, 58) f32 binary {0,1};  w: (256, 256, 3, 3) f32
// out: (32, 256, 56, 56) f32 = alpha[o]*(2S - 2304), S = XNOR matches
// out = fma(-2*alpha[o], P, 2304*alpha[o]),  P = popcount(xbits ^ wbits)

#define BATCH 32
#define C_IN 256
#define OCH 256
#define HIN 58
#define WIN2 58
#define HOUT 56
#define WOUT 56
#define TAPS 9
#define WWORDS 8            // 256 channels / 32 bits
#define KW 72               // TAPS * WWORDS
#define HWIN (HIN * WIN2)   // 3364
#define HWOUT (HOUT * WOUT) // 3136
#define NPOS (BATCH * HWIN) // 107648

// ---------------------------------------------------------------------------
// Kernel 1: bit-pack x along channels. Thread ↔ (word w, 2 consecutive pos).
// 430,592 threads = 1682 blocks exactly; 6.6 waves/SIMD.
// Reads: float2 (8B/lane, 512B/wave-instr, contiguous across lanes).
// ---------------------------------------------------------------------------
__global__ __launch_bounds__(256) void pack_x_kernel(
    const float* __restrict__ x, uint32_t* __restrict__ xp)
{
    int t = blockIdx.x * 256 + threadIdx.x;
    int w = t / (NPOS / 2);
    int q = t - w * (NPOS / 2);
    int p = 2 * q;                               // even; HWIN even so pair stays in-image
    int b = p / HWIN;
    int r = p - b * HWIN;
    const float* xb = x + ((size_t)(b * C_IN + w * 32)) * HWIN + r;
    uint32_t m0 = 0u, m1 = 0u;
    #pragma unroll
    for (int j = 0; j < 32; ++j) {
        float2 v = *(const float2*)(xb + (size_t)j * HWIN);
        m0 |= (v.x > 0.5f ? 1u : 0u) << j;
        m1 |= (v.y > 0.5f ? 1u : 0u) << j;
    }
    xp[(size_t)p * WWORDS + w] = m0;
    xp[(size_t)(p + 1) * WWORDS + w] = m1;
}

// ---------------------------------------------------------------------------
// Kernel 2: pack weights TAP-MAJOR (wq[tap][o][8]) + per-o scale/bias.
// Tap-major makes the main kernel's o-loop weight reads contiguous -> s_load.
// ---------------------------------------------------------------------------
__global__ __launch_bounds__(256) void pack_w_kernel(
    const float* __restrict__ wt, uint32_t* __restrict__ wq,
    float* __restrict__ sA, float* __restrict__ sB)
{
    int o = blockIdx.x;
    int c = threadIdx.x;
    const float* wb = wt + ((size_t)o * C_IN + c) * TAPS;
    float wv[TAPS];
    float s = 0.f;
    #pragma unroll
    for (int t = 0; t < TAPS; ++t) {
        wv[t] = wb[t];
        s += fabsf(wv[t]);
    }
    int wave = c >> 6, lane = c & 63;
    #pragma unroll
    for (int t = 0; t < TAPS; ++t) {
        unsigned long long m = __ballot(wv[t] >= 0.0f);
        if (lane == 0) {
            wq[((size_t)t * OCH + o) * WWORDS + wave * 2]     = (uint32_t)m;
            wq[((size_t)t * OCH + o) * WWORDS + wave * 2 + 1] = (uint32_t)(m >> 32);
        }
    }
    __shared__ float red[256];
    red[c] = s;
    __syncthreads();
    for (int off = 128; off > 0; off >>= 1) {
        if (c < off) red[c] += red[c + off];
        __syncthreads();
    }
    if (c == 0) {
        float alpha = red[0] / (float)(C_IN * HWIN);   // n = C*H*W per reference
        sA[o] = -2.0f * alpha;
        sB[o] = (float)(C_IN * TAPS) * alpha;          // 2304 * alpha
    }
}

// ---------------------------------------------------------------------------
// Kernel 3: main. Thread ↔ output position; 64 o-channels per thread held as
// 32 PACKED u32 accumulators (two 16-bit popcount halves; max 2304 < 2^16).
// x streamed one 8-word tap at a time (8 live VGPRs) -> no AGPR parking
// (R2: 72-word resident window got parked in AGPRs, +50% VALU ops).
// Weights: tap-major, wave-uniform -> s_load_dwordx16 batches via K$.
// ---------------------------------------------------------------------------
__global__ __launch_bounds__(256, 3) void xnor_main_kernel(
    const uint32_t* __restrict__ xp, const uint32_t* __restrict__ wq,
    const float* __restrict__ sA, const float* __restrict__ sB,
    float* __restrict__ out)
{
    int m = blockIdx.x * 256 + threadIdx.x;      // 392 blocks exactly
    int b = m / HWOUT;
    int r = m - b * HWOUT;
    int oy = r / WOUT;
    int ox = r - oy * WOUT;
    int obase = blockIdx.y * 64;

    uint32_t acc[32];
    #pragma unroll
    for (int i = 0; i < 32; ++i) acc[i] = 0u;

    const uint32_t* wqo = wq + (size_t)obase * WWORDS;

    #pragma unroll 1   // full unroll would be ~80KB of code -> I$ thrash
    for (int tap = 0; tap < TAPS; ++tap) {
        int dy = tap / 3, dx = tap - dy * 3;
        const uint4* src = (const uint4*)(xp +
            (((size_t)b * HIN + (oy + dy)) * WIN2 + (ox + dx)) * WWORDS);
        uint4 x0 = src[0];
        uint4 x1 = src[1];
        uint32_t xw[WWORDS] = {x0.x, x0.y, x0.z, x0.w, x1.x, x1.y, x1.z, x1.w};
        const uint32_t* wt8 = wqo + (size_t)tap * OCH * WWORDS;
        #pragma unroll
        for (int oo = 0; oo < 64; oo += 2) {
            const uint32_t* w0 = wt8 + oo * WWORDS;   // uniform -> scalar loads
            uint32_t P0 = 0, P1 = 0;
            #pragma unroll
            for (int k = 0; k < 8; ++k) P0 += __popc(w0[k] ^ xw[k]);
            #pragma unroll
            for (int k = 0; k < 8; ++k) P1 += __popc(w0[8 + k] ^ xw[k]);
            acc[oo >> 1] += P0 + (P1 << 16);          // lshl_add + add
        }
    }

    size_t ob = ((size_t)b * OCH + obase) * HWOUT + (size_t)oy * WOUT + ox;
    #pragma unroll
    for (int oo = 0; oo < 64; oo += 2) {
        uint32_t a = acc[oo >> 1];
        float P0 = (float)(a & 0xFFFFu);
        float P1 = (float)(a >> 16);
        int o0 = obase + oo;
        out[ob + (size_t)oo * HWOUT]       = fmaf(sA[o0],     P0, sB[o0]);
        out[ob + (size_t)(oo + 1) * HWOUT] = fmaf(sA[o0 + 1], P1, sB[o0 + 1]);
    }
}

// ---------------------------------------------------------------------------
extern "C" void kernel_launch(void* const* d_in, const int* in_sizes, int n_in,
                              void* d_out, int out_size, void* d_ws, size_t ws_size,
                              hipStream_t stream)
{
    const float* x  = (const float*)d_in[0];
    const float* wt = (const float*)d_in[1];
    float* out = (float*)d_out;

    char* ws = (char*)d_ws;
    uint32_t* xp = (uint32_t*)ws;                               // 3,444,736 B
    uint32_t* wq = (uint32_t*)(ws + 3444736);                   //    73,728 B
    float*    sA = (float*)(ws + 3444736 + 73728);              //     1,024 B
    float*    sB = (float*)(ws + 3444736 + 73728 + 1024);       //     1,024 B

    // 1) pack x: 430,592 threads / 256 = 1682 blocks exactly
    pack_x_kernel<<<dim3(1682), dim3(256), 0, stream>>>(x, xp);

    // 2) pack weights (tap-major) + scales
    pack_w_kernel<<<dim3(OCH), dim3(256), 0, stream>>>(wt, wq, sA, sB);

    // 3) main: 392 blocks x 4 o-groups
    xnor_main_kernel<<<dim3(392, 4), dim3(256), 0, stream>>>(xp, wq, sA, sB, out);
}

// Round 4
// 317.846 us; speedup vs baseline: 1.0659x; 1.0659x over previous
//
#include <hip/hip_runtime.h>
#include <stdint.h>

// x: (32, 256, 58, 58) f32 binary {0,1};  w: (256, 256, 3, 3) f32
// out: (32, 256, 56, 56) f32 = alpha[o]*(2S - 2304), S = XNOR matches
// out = fma(-2*alpha[o], P, 2304*alpha[o]),  P = popcount(xbits ^ wbits)

#define BATCH 32
#define C_IN 256
#define OCH 256
#define HIN 58
#define WIN2 58
#define HOUT 56
#define WOUT 56
#define TAPS 9
#define WWORDS 8            // 256 channels / 32 bits
#define HWIN (HIN * WIN2)   // 3364
#define HWOUT (HOUT * WOUT) // 3136
#define NPOS (BATCH * HWIN) // 107648
#define OGRP 32             // o-channels per block (8 groups)

// ---------------------------------------------------------------------------
// Kernel 1: bit-pack x along channels. Thread ↔ (word w, 2 consecutive pos).
// ---------------------------------------------------------------------------
__global__ __launch_bounds__(256) void pack_x_kernel(
    const float* __restrict__ x, uint32_t* __restrict__ xp)
{
    int t = blockIdx.x * 256 + threadIdx.x;
    int w = t / (NPOS / 2);
    int q = t - w * (NPOS / 2);
    int p = 2 * q;                               // even; HWIN even so pair stays in-image
    int b = p / HWIN;
    int r = p - b * HWIN;
    const float* xb = x + ((size_t)(b * C_IN + w * 32)) * HWIN + r;
    uint32_t m0 = 0u, m1 = 0u;
    #pragma unroll
    for (int j = 0; j < 32; ++j) {
        float2 v = *(const float2*)(xb + (size_t)j * HWIN);
        m0 |= (v.x > 0.5f ? 1u : 0u) << j;
        m1 |= (v.y > 0.5f ? 1u : 0u) << j;
    }
    xp[(size_t)p * WWORDS + w] = m0;
    xp[(size_t)(p + 1) * WWORDS + w] = m1;
}

// ---------------------------------------------------------------------------
// Kernel 2: pack weights TAP-MAJOR (wq[tap][o][8]) + per-o scale/bias.
// ---------------------------------------------------------------------------
__global__ __launch_bounds__(256) void pack_w_kernel(
    const float* __restrict__ wt, uint32_t* __restrict__ wq,
    float* __restrict__ sA, float* __restrict__ sB)
{
    int o = blockIdx.x;
    int c = threadIdx.x;
    const float* wb = wt + ((size_t)o * C_IN + c) * TAPS;
    float wv[TAPS];
    float s = 0.f;
    #pragma unroll
    for (int t = 0; t < TAPS; ++t) {
        wv[t] = wb[t];
        s += fabsf(wv[t]);
    }
    int wave = c >> 6, lane = c & 63;
    #pragma unroll
    for (int t = 0; t < TAPS; ++t) {
        unsigned long long m = __ballot(wv[t] >= 0.0f);
        if (lane == 0) {
            wq[((size_t)t * OCH + o) * WWORDS + wave * 2]     = (uint32_t)m;
            wq[((size_t)t * OCH + o) * WWORDS + wave * 2 + 1] = (uint32_t)(m >> 32);
        }
    }
    __shared__ float red[256];
    red[c] = s;
    __syncthreads();
    for (int off = 128; off > 0; off >>= 1) {
        if (c < off) red[c] += red[c + off];
        __syncthreads();
    }
    if (c == 0) {
        float alpha = red[0] / (float)(C_IN * HWIN);   // n = C*H*W per reference
        sA[o] = -2.0f * alpha;
        sB[o] = (float)(C_IN * TAPS) * alpha;          // 2304 * alpha
    }
}

// ---------------------------------------------------------------------------
// Kernel 3: main. Thread ↔ output position; 32 o-channels per block, staged
// in LDS (weights read as same-address ds_read_b128 BROADCASTS -> zero TA
// pipe pressure; R3: per-o global vector loads saturated the texture pipe,
// co-limiting with VALU at 60%). Accumulators: 16 u32, two 16-bit halves.
// Popcounts built as 4 independent 4-deep v_bcnt chains per o-pair so the
// VALU pipelines at moderate occupancy (R3 had 8-deep serial chains).
// ---------------------------------------------------------------------------
__global__ __launch_bounds__(256, 4) void xnor_main_kernel(
    const uint32_t* __restrict__ xp, const uint32_t* __restrict__ wq,
    const float* __restrict__ sA, const float* __restrict__ sB,
    float* __restrict__ out)
{
    __shared__ uint32_t wlds[TAPS * OGRP * WWORDS];   // 2304 words = 9216 B

    int obase = blockIdx.y * OGRP;
    // Stage this block's weights: 2304 words / 256 threads = 9 each.
    #pragma unroll
    for (int i = 0; i < 9; ++i) {
        int L = threadIdx.x + i * 256;
        int tap = L >> 8;                  // L / (OGRP*WWORDS)
        int oo  = (L >> 3) & (OGRP - 1);
        int k   = L & 7;
        wlds[L] = wq[(((size_t)tap * OCH) + obase + oo) * WWORDS + k];
    }
    __syncthreads();

    int m = blockIdx.x * 256 + threadIdx.x;      // 392 blocks exactly
    int b = m / HWOUT;
    int r = m - b * HWOUT;
    int oy = r / WOUT;
    int ox = r - oy * WOUT;

    uint32_t acc[OGRP / 2];
    #pragma unroll
    for (int i = 0; i < OGRP / 2; ++i) acc[i] = 0u;

    #pragma unroll 1
    for (int tap = 0; tap < TAPS; ++tap) {
        int dy = tap / 3, dx = tap - dy * 3;
        const uint4* src = (const uint4*)(xp +
            (((size_t)b * HIN + (oy + dy)) * WIN2 + (ox + dx)) * WWORDS);
        uint4 x0 = src[0];
        uint4 x1 = src[1];
        const uint4* wl = (const uint4*)&wlds[tap * OGRP * WWORDS];
        #pragma unroll
        for (int oo = 0; oo < OGRP; oo += 2) {
            uint4 wa = wl[oo * 2 + 0];           // o0 words 0-3   (broadcast)
            uint4 wb2 = wl[oo * 2 + 1];          // o0 words 4-7
            uint4 wc = wl[oo * 2 + 2];           // o1 words 0-3
            uint4 wd = wl[oo * 2 + 3];           // o1 words 4-7
            uint32_t q0 = __popc(wa.x ^ x0.x) + __popc(wa.y ^ x0.y)
                        + __popc(wa.z ^ x0.z) + __popc(wa.w ^ x0.w);
            uint32_t q1 = __popc(wb2.x ^ x1.x) + __popc(wb2.y ^ x1.y)
                        + __popc(wb2.z ^ x1.z) + __popc(wb2.w ^ x1.w);
            uint32_t q2 = __popc(wc.x ^ x0.x) + __popc(wc.y ^ x0.y)
                        + __popc(wc.z ^ x0.z) + __popc(wc.w ^ x0.w);
            uint32_t q3 = __popc(wd.x ^ x1.x) + __popc(wd.y ^ x1.y)
                        + __popc(wd.z ^ x1.z) + __popc(wd.w ^ x1.w);
            acc[oo >> 1] += (q0 + q1) + ((q2 + q3) << 16);
        }
    }

    size_t ob = ((size_t)b * OCH + obase) * HWOUT + (size_t)oy * WOUT + ox;
    #pragma unroll
    for (int oo = 0; oo < OGRP; oo += 2) {
        uint32_t a = acc[oo >> 1];
        float P0 = (float)(a & 0xFFFFu);
        float P1 = (float)(a >> 16);
        int o0 = obase + oo;
        out[ob + (size_t)oo * HWOUT]       = fmaf(sA[o0],     P0, sB[o0]);
        out[ob + (size_t)(oo + 1) * HWOUT] = fmaf(sA[o0 + 1], P1, sB[o0 + 1]);
    }
}

// ---------------------------------------------------------------------------
extern "C" void kernel_launch(void* const* d_in, const int* in_sizes, int n_in,
                              void* d_out, int out_size, void* d_ws, size_t ws_size,
                              hipStream_t stream)
{
    const float* x  = (const float*)d_in[0];
    const float* wt = (const float*)d_in[1];
    float* out = (float*)d_out;

    char* ws = (char*)d_ws;
    uint32_t* xp = (uint32_t*)ws;                               // 3,444,736 B
    uint32_t* wq = (uint32_t*)(ws + 3444736);                   //    73,728 B
    float*    sA = (float*)(ws + 3444736 + 73728);              //     1,024 B
    float*    sB = (float*)(ws + 3444736 + 73728 + 1024);       //     1,024 B

    // 1) pack x: 430,592 threads / 256 = 1682 blocks exactly
    pack_x_kernel<<<dim3(1682), dim3(256), 0, stream>>>(x, xp);

    // 2) pack weights (tap-major) + scales
    pack_w_kernel<<<dim3(OCH), dim3(256), 0, stream>>>(wt, wq, sA, sB);

    // 3) main: 392 position-blocks x 8 o-groups of 32
    xnor_main_kernel<<<dim3(392, 8), dim3(256), 0, stream>>>(xp, wq, sA, sB, out);
}